// Round 1
// baseline (819.386 us; speedup 1.0000x reference)
//
#include <hip/hip_runtime.h>

// FillSimNet: 4-layer GCN forward.
// Pipeline per call:
//   1. deg/dis + in-degree counts (atomics)
//   2. block-scan -> row_ptr, fill CSR (by dst) with norm values
//   3. encoder MLP (8->64 relu 64->64)
//   4. 4x { t = h @ W (LDS-staged dense) ; h = relu(sum norm*t[src] + b) }
//   5. decoder MLP (64->64 relu 64->1)

constexpr int NN   = 100000;
constexpr int NE   = 1600000;
constexpr int INPD = 8;
constexpr int EMBD = 64;
constexpr int NLAY = 4;
constexpr int SCAN_B = 1024;
constexpr int SCAN_NBLK = (NN + SCAN_B - 1) / SCAN_B; // 98

__global__ void k_init(float* deg, int* cnt) {
    int i = blockIdx.x * blockDim.x + threadIdx.x;
    if (i < NN) { deg[i] = 1.0f; cnt[i] = 0; }   // self-loop weight = 1
}

__global__ void k_count(const int* ei, const float* w, float* deg, int* cnt) {
    int e = blockIdx.x * blockDim.x + threadIdx.x;
    if (e < NE) {
        int d = ei[NE + e];
        atomicAdd(&deg[d], w[e]);
        atomicAdd(&cnt[d], 1);
    }
}

__global__ void k_dis(float* deg) {
    int i = blockIdx.x * blockDim.x + threadIdx.x;
    if (i < NN) deg[i] = 1.0f / sqrtf(deg[i]);   // deg >= 1 always
}

__global__ __launch_bounds__(SCAN_B) void k_scan1(const int* cnt, int* incl, int* partials) {
    __shared__ int s[SCAN_B];
    int tid = threadIdx.x;
    int i = blockIdx.x * SCAN_B + tid;
    int v = (i < NN) ? cnt[i] : 0;
    s[tid] = v;
    __syncthreads();
    for (int off = 1; off < SCAN_B; off <<= 1) {
        int t = (tid >= off) ? s[tid - off] : 0;
        __syncthreads();
        s[tid] += t;
        __syncthreads();
    }
    if (i < NN) incl[i] = s[tid];
    if (tid == SCAN_B - 1) partials[blockIdx.x] = s[tid];
}

__global__ void k_scan2(int* partials) {
    if (threadIdx.x == 0 && blockIdx.x == 0) {
        int run = 0;
        for (int b = 0; b < SCAN_NBLK; ++b) {
            int t = partials[b];
            partials[b] = run;
            run += t;
        }
        partials[SCAN_NBLK] = run;  // == NE
    }
}

__global__ void k_scan3(const int* cnt, const int* incl, const int* partials,
                        int* row_ptr, int* cursor) {
    int i = blockIdx.x * blockDim.x + threadIdx.x;
    if (i < NN) {
        int rp = incl[i] - cnt[i] + partials[i >> 10];
        row_ptr[i] = rp;
        cursor[i] = rp;
        if (i == 0) row_ptr[NN] = partials[SCAN_NBLK];
    }
}

__global__ void k_fill(const int* ei, const float* w, const float* dis,
                       int* cursor, int* col, float* val) {
    int e = blockIdx.x * blockDim.x + threadIdx.x;
    if (e < NE) {
        int s = ei[e];
        int d = ei[NE + e];
        int pos = atomicAdd(&cursor[d], 1);
        col[pos] = s;
        val[pos] = dis[s] * w[e] * dis[d];
    }
}

// encoder: h = relu(x@W1+b1)@W2 + b2 ; 16 nodes per 256-thread block
__global__ __launch_bounds__(256) void k_encoder(const float* __restrict__ x,
                                                 const float* __restrict__ w1,
                                                 const float* __restrict__ b1,
                                                 const float* __restrict__ w2,
                                                 const float* __restrict__ b2,
                                                 float* __restrict__ h) {
    __shared__ float sW1[INPD * EMBD];
    __shared__ float sW2[EMBD * EMBD];
    __shared__ float sB1[EMBD];
    __shared__ float sB2[EMBD];
    __shared__ float sZ[16][EMBD];
    int tid = threadIdx.x;
    for (int i = tid; i < INPD * EMBD; i += 256) sW1[i] = w1[i];
    for (int i = tid; i < EMBD * EMBD; i += 256) sW2[i] = w2[i];
    if (tid < EMBD) { sB1[tid] = b1[tid]; sB2[tid] = b2[tid]; }
    __syncthreads();
    int base = blockIdx.x * 16;
    #pragma unroll
    for (int it = 0; it < 4; ++it) {
        int item = tid + it * 256;
        int nl = item >> 6, j = item & 63;
        int node = base + nl;
        float acc = sB1[j];
        if (node < NN) {
            const float* xr = x + (size_t)node * INPD;
            #pragma unroll
            for (int k = 0; k < INPD; ++k) acc += xr[k] * sW1[k * EMBD + j];
        }
        sZ[nl][j] = fmaxf(acc, 0.0f);
    }
    __syncthreads();
    #pragma unroll
    for (int it = 0; it < 4; ++it) {
        int item = tid + it * 256;
        int nl = item >> 6, j2 = item & 63;
        int node = base + nl;
        if (node < NN) {
            float acc = sB2[j2];
            for (int j = 0; j < EMBD; ++j) acc += sZ[nl][j] * sW2[j * EMBD + j2];
            h[(size_t)node * EMBD + j2] = acc;
        }
    }
}

// t = h @ W (no bias/relu here)
__global__ __launch_bounds__(256) void k_transform(const float* __restrict__ hin,
                                                   const float* __restrict__ W,
                                                   float* __restrict__ tout) {
    __shared__ float sW[EMBD * EMBD];
    __shared__ float sH[16][EMBD];
    int tid = threadIdx.x;
    for (int i = tid; i < EMBD * EMBD; i += 256) sW[i] = W[i];
    int base = blockIdx.x * 16;
    #pragma unroll
    for (int it = 0; it < 4; ++it) {
        int item = tid + it * 256;
        int nl = item >> 6, j = item & 63;
        int node = base + nl;
        sH[nl][j] = (node < NN) ? hin[(size_t)node * EMBD + j] : 0.0f;
    }
    __syncthreads();
    #pragma unroll
    for (int it = 0; it < 4; ++it) {
        int item = tid + it * 256;
        int nl = item >> 6, j2 = item & 63;
        int node = base + nl;
        if (node < NN) {
            float acc = 0.0f;
            for (int j = 0; j < EMBD; ++j) acc += sH[nl][j] * sW[j * EMBD + j2];
            tout[(size_t)node * EMBD + j2] = acc;
        }
    }
}

// h = relu( dis[n]^2 * t[n] + sum_e val[e]*t[col[e]] + b ) ; 16 lanes per node
__global__ __launch_bounds__(256) void k_aggregate(const float* __restrict__ t,
                                                   const float* __restrict__ dis,
                                                   const int* __restrict__ row_ptr,
                                                   const int* __restrict__ col,
                                                   const float* __restrict__ val,
                                                   const float* __restrict__ bias,
                                                   float* __restrict__ hout) {
    int tid = threadIdx.x;
    int g = tid >> 4, l = tid & 15;
    int node = blockIdx.x * 16 + g;
    if (node >= NN) return;
    const float4* t4 = (const float4*)t;
    float dsn = dis[node];
    float sn = dsn * dsn;
    float4 acc = t4[(size_t)node * 16 + l];
    acc.x *= sn; acc.y *= sn; acc.z *= sn; acc.w *= sn;
    int beg = row_ptr[node], end = row_ptr[node + 1];
    for (int e = beg; e < end; ++e) {
        int s = col[e];
        float v = val[e];
        float4 tv = t4[(size_t)s * 16 + l];
        acc.x += v * tv.x; acc.y += v * tv.y; acc.z += v * tv.z; acc.w += v * tv.w;
    }
    float4 b = ((const float4*)bias)[l];
    acc.x = fmaxf(acc.x + b.x, 0.0f);
    acc.y = fmaxf(acc.y + b.y, 0.0f);
    acc.z = fmaxf(acc.z + b.z, 0.0f);
    acc.w = fmaxf(acc.w + b.w, 0.0f);
    ((float4*)hout)[(size_t)node * 16 + l] = acc;
}

// out = relu(h@W1+b1)@W2 + b2 (OUT=1) ; one wave per node, 4 nodes/wave serial
__global__ __launch_bounds__(256) void k_decoder(const float* __restrict__ h,
                                                 const float* __restrict__ w1,
                                                 const float* __restrict__ b1,
                                                 const float* __restrict__ w2,
                                                 const float* __restrict__ b2,
                                                 float* __restrict__ out) {
    __shared__ float sW1[EMBD * EMBD];
    __shared__ float sB1[EMBD];
    __shared__ float sW2[EMBD];
    int tid = threadIdx.x;
    for (int i = tid; i < EMBD * EMBD; i += 256) sW1[i] = w1[i];
    if (tid < EMBD) { sB1[tid] = b1[tid]; sW2[tid] = w2[tid]; }
    __syncthreads();
    int wave = tid >> 6, lane = tid & 63;
    float db2 = b2[0];
    #pragma unroll
    for (int it = 0; it < 4; ++it) {
        int node = blockIdx.x * 16 + wave * 4 + it;
        if (node >= NN) continue;
        const float* hr = h + (size_t)node * EMBD;
        float acc = sB1[lane];
        for (int k = 0; k < EMBD; ++k) acc += hr[k] * sW1[k * EMBD + lane];
        acc = fmaxf(acc, 0.0f);
        float r = acc * sW2[lane];
        for (int o = 32; o > 0; o >>= 1) r += __shfl_down(r, o);
        if (lane == 0) out[node] = r + db2;
    }
}

extern "C" void kernel_launch(void* const* d_in, const int* in_sizes, int n_in,
                              void* d_out, int out_size, void* d_ws, size_t ws_size,
                              hipStream_t stream) {
    const float* x      = (const float*)d_in[0];
    const int*   ei     = (const int*)  d_in[1];
    const float* ew     = (const float*)d_in[2];
    const float* enc_w1 = (const float*)d_in[3];
    const float* enc_b1 = (const float*)d_in[4];
    const float* enc_w2 = (const float*)d_in[5];
    const float* enc_b2 = (const float*)d_in[6];
    const float* gcn_w  = (const float*)d_in[7];
    const float* gcn_b  = (const float*)d_in[8];
    const float* dec_w1 = (const float*)d_in[9];
    const float* dec_b1 = (const float*)d_in[10];
    const float* dec_w2 = (const float*)d_in[11];
    const float* dec_b2 = (const float*)d_in[12];
    float* out = (float*)d_out;

    char* ws = (char*)d_ws;
    size_t off = 0;
    auto alloc = [&](size_t bytes) -> void* {
        void* p = (void*)(ws + off);
        off += (bytes + 511) & ~(size_t)511;
        return p;
    };
    float* deg      = (float*)alloc(NN * 4);          // becomes dis in-place
    int*   cnt      = (int*)  alloc(NN * 4);
    int*   incl     = (int*)  alloc(NN * 4);
    int*   partials = (int*)  alloc(256 * 4);
    int*   row_ptr  = (int*)  alloc((NN + 1) * 4);
    int*   cursor   = (int*)  alloc(NN * 4);
    int*   csr_col  = (int*)  alloc((size_t)NE * 4);
    float* csr_val  = (float*)alloc((size_t)NE * 4);
    float* hbuf     = (float*)alloc((size_t)NN * EMBD * 4);
    float* tbuf     = (float*)alloc((size_t)NN * EMBD * 4);
    (void)ws_size; (void)n_in; (void)in_sizes; (void)out_size;

    int gN   = (NN + 255) / 256;
    int gE   = (NE + 255) / 256;
    int gT16 = (NN + 15) / 16;

    k_init<<<gN, 256, 0, stream>>>(deg, cnt);
    k_count<<<gE, 256, 0, stream>>>(ei, ew, deg, cnt);
    k_dis<<<gN, 256, 0, stream>>>(deg);
    k_scan1<<<SCAN_NBLK, SCAN_B, 0, stream>>>(cnt, incl, partials);
    k_scan2<<<1, 1, 0, stream>>>(partials);
    k_scan3<<<gN, 256, 0, stream>>>(cnt, incl, partials, row_ptr, cursor);
    k_fill<<<gE, 256, 0, stream>>>(ei, ew, deg, cursor, csr_col, csr_val);

    k_encoder<<<gT16, 256, 0, stream>>>(x, enc_w1, enc_b1, enc_w2, enc_b2, hbuf);

    for (int layer = 0; layer < NLAY; ++layer) {
        k_transform<<<gT16, 256, 0, stream>>>(hbuf, gcn_w + (size_t)layer * EMBD * EMBD, tbuf);
        k_aggregate<<<gT16, 256, 0, stream>>>(tbuf, deg, row_ptr, csr_col, csr_val,
                                              gcn_b + (size_t)layer * EMBD, hbuf);
    }

    k_decoder<<<gT16, 256, 0, stream>>>(hbuf, dec_w1, dec_b1, dec_w2, dec_b2, out);
}

// Round 2
// 669.194 us; speedup vs baseline: 1.2244x; 1.2244x over previous
//
#include <hip/hip_runtime.h>

// FillSimNet: 4-layer GCN forward.
//   1. packed u64 atomics: hi32 = in-degree count, lo32 = fixed-point (2^24) weight sum
//   2. block-scan -> row_ptr, fill CSR (by dst) with packed (col, norm) int2
//   3. encoder MLP (8->64 relu 64->64)
//   4. 4x fused layer: agg = SpMM(norm, h); h = relu(agg @ W + b)
//      (uses linearity: sum norm*(hW) == (sum norm*h) W)
//   5. decoder MLP (64->64 relu 64->1)

constexpr int NN   = 100000;
constexpr int NE   = 1600000;
constexpr int INPD = 8;
constexpr int EMBD = 64;
constexpr int NLAY = 4;
constexpr int SCAN_B = 1024;
constexpr int SCAN_NBLK = (NN + SCAN_B - 1) / SCAN_B; // 98
constexpr float FPSCALE = 16777216.0f;   // 2^24

__global__ void k_init(unsigned long long* packed) {
    int i = blockIdx.x * blockDim.x + threadIdx.x;
    if (i < NN) packed[i] = (unsigned long long)(1u << 24);  // self-loop weight 1.0, count 0
}

__global__ void k_count(const int* __restrict__ ei, const float* __restrict__ w,
                        unsigned long long* __restrict__ packed) {
    int e = blockIdx.x * blockDim.x + threadIdx.x;
    if (e < NE) {
        int d = ei[NE + e];
        unsigned int fx = (unsigned int)(w[e] * FPSCALE + 0.5f);
        atomicAdd(&packed[d], (1ull << 32) | (unsigned long long)fx);
    }
}

__global__ void k_dis(const unsigned long long* __restrict__ packed, float* __restrict__ dis) {
    int i = blockIdx.x * blockDim.x + threadIdx.x;
    if (i < NN) {
        float deg = (float)(unsigned int)(packed[i] & 0xffffffffull) * (1.0f / FPSCALE);
        dis[i] = 1.0f / sqrtf(deg);   // deg >= 1 always
    }
}

__global__ __launch_bounds__(SCAN_B) void k_scan1(const unsigned long long* __restrict__ packed,
                                                  int* incl, int* partials) {
    __shared__ int s[SCAN_B];
    int tid = threadIdx.x;
    int i = blockIdx.x * SCAN_B + tid;
    int v = (i < NN) ? (int)(packed[i] >> 32) : 0;
    s[tid] = v;
    __syncthreads();
    for (int off = 1; off < SCAN_B; off <<= 1) {
        int t = (tid >= off) ? s[tid - off] : 0;
        __syncthreads();
        s[tid] += t;
        __syncthreads();
    }
    if (i < NN) incl[i] = s[tid];
    if (tid == SCAN_B - 1) partials[blockIdx.x] = s[tid];
}

__global__ void k_scan2(int* partials) {
    if (threadIdx.x == 0 && blockIdx.x == 0) {
        int run = 0;
        for (int b = 0; b < SCAN_NBLK; ++b) {
            int t = partials[b];
            partials[b] = run;
            run += t;
        }
        partials[SCAN_NBLK] = run;  // == NE
    }
}

__global__ void k_scan3(const unsigned long long* __restrict__ packed,
                        const int* __restrict__ incl, const int* __restrict__ partials,
                        int* row_ptr, int* cursor) {
    int i = blockIdx.x * blockDim.x + threadIdx.x;
    if (i < NN) {
        int c = (int)(packed[i] >> 32);
        int rp = incl[i] - c + partials[i >> 10];
        row_ptr[i] = rp;
        cursor[i] = rp;
        if (i == 0) row_ptr[NN] = partials[SCAN_NBLK];
    }
}

__global__ void k_fill(const int* __restrict__ ei, const float* __restrict__ w,
                       const float* __restrict__ dis,
                       int* __restrict__ cursor, int2* __restrict__ edges) {
    int e = blockIdx.x * blockDim.x + threadIdx.x;
    if (e < NE) {
        int s = ei[e];
        int d = ei[NE + e];
        int pos = atomicAdd(&cursor[d], 1);
        float nv = dis[s] * w[e] * dis[d];
        edges[pos] = make_int2(s, __float_as_int(nv));
    }
}

// encoder: h = relu(x@W1+b1)@W2 + b2 ; 16 nodes per 256-thread block
__global__ __launch_bounds__(256) void k_encoder(const float* __restrict__ x,
                                                 const float* __restrict__ w1,
                                                 const float* __restrict__ b1,
                                                 const float* __restrict__ w2,
                                                 const float* __restrict__ b2,
                                                 float* __restrict__ h) {
    __shared__ float sW1[INPD * EMBD];
    __shared__ float sW2[EMBD * EMBD];
    __shared__ float sB1[EMBD];
    __shared__ float sB2[EMBD];
    __shared__ float sZ[16][EMBD];
    int tid = threadIdx.x;
    for (int i = tid; i < INPD * EMBD; i += 256) sW1[i] = w1[i];
    for (int i = tid; i < EMBD * EMBD; i += 256) sW2[i] = w2[i];
    if (tid < EMBD) { sB1[tid] = b1[tid]; sB2[tid] = b2[tid]; }
    __syncthreads();
    int base = blockIdx.x * 16;
    #pragma unroll
    for (int it = 0; it < 4; ++it) {
        int item = tid + it * 256;
        int nl = item >> 6, j = item & 63;
        int node = base + nl;
        float acc = sB1[j];
        if (node < NN) {
            const float* xr = x + (size_t)node * INPD;
            #pragma unroll
            for (int k = 0; k < INPD; ++k) acc += xr[k] * sW1[k * EMBD + j];
        }
        sZ[nl][j] = fmaxf(acc, 0.0f);
    }
    __syncthreads();
    #pragma unroll
    for (int it = 0; it < 4; ++it) {
        int item = tid + it * 256;
        int nl = item >> 6, j2 = item & 63;
        int node = base + nl;
        if (node < NN) {
            float acc = sB2[j2];
            for (int j = 0; j < EMBD; ++j) acc += sZ[nl][j] * sW2[j * EMBD + j2];
            h[(size_t)node * EMBD + j2] = acc;
        }
    }
}

// fused layer: agg = dis[n]^2*h[n] + sum_e norm[e]*h[col[e]] ; hout = relu(agg @ W + b)
__global__ __launch_bounds__(256) void k_layer(const float* __restrict__ hin,
                                               const float* __restrict__ dis,
                                               const int* __restrict__ row_ptr,
                                               const int2* __restrict__ edges,
                                               const float* __restrict__ W,
                                               const float* __restrict__ bias,
                                               float* __restrict__ hout) {
    __shared__ float sW[EMBD * EMBD];
    __shared__ float sB[EMBD];
    __shared__ float sA[16][EMBD];
    int tid = threadIdx.x;
    for (int i = tid; i < EMBD * EMBD; i += 256) sW[i] = W[i];
    if (tid < EMBD) sB[tid] = bias[tid];

    int g = tid >> 4, l = tid & 15;
    int node = blockIdx.x * 16 + g;
    const float4* h4 = (const float4*)hin;
    float4 acc = make_float4(0.f, 0.f, 0.f, 0.f);
    if (node < NN) {
        float dsn = dis[node];
        float sn = dsn * dsn;
        acc = h4[(size_t)node * 16 + l];
        acc.x *= sn; acc.y *= sn; acc.z *= sn; acc.w *= sn;
        int beg = row_ptr[node], end = row_ptr[node + 1];
        for (int e = beg; e < end; ++e) {
            int2 ev = edges[e];
            float v = __int_as_float(ev.y);
            float4 tv = h4[(size_t)ev.x * 16 + l];
            acc.x += v * tv.x; acc.y += v * tv.y; acc.z += v * tv.z; acc.w += v * tv.w;
        }
    }
    ((float4*)&sA[g][0])[l] = acc;
    __syncthreads();

    int base = blockIdx.x * 16;
    #pragma unroll
    for (int it = 0; it < 4; ++it) {
        int item = tid + it * 256;
        int nl = item >> 6, j2 = item & 63;
        int onode = base + nl;
        if (onode < NN) {
            float o = sB[j2];
            for (int k = 0; k < EMBD; ++k) o += sA[nl][k] * sW[k * EMBD + j2];
            hout[(size_t)onode * EMBD + j2] = fmaxf(o, 0.0f);
        }
    }
}

// out = relu(h@W1+b1)@W2 + b2 (OUT=1) ; one wave per node, 4 nodes/wave serial
__global__ __launch_bounds__(256) void k_decoder(const float* __restrict__ h,
                                                 const float* __restrict__ w1,
                                                 const float* __restrict__ b1,
                                                 const float* __restrict__ w2,
                                                 const float* __restrict__ b2,
                                                 float* __restrict__ out) {
    __shared__ float sW1[EMBD * EMBD];
    __shared__ float sB1[EMBD];
    __shared__ float sW2[EMBD];
    int tid = threadIdx.x;
    for (int i = tid; i < EMBD * EMBD; i += 256) sW1[i] = w1[i];
    if (tid < EMBD) { sB1[tid] = b1[tid]; sW2[tid] = w2[tid]; }
    __syncthreads();
    int wave = tid >> 6, lane = tid & 63;
    float db2 = b2[0];
    #pragma unroll
    for (int it = 0; it < 4; ++it) {
        int node = blockIdx.x * 16 + wave * 4 + it;
        if (node >= NN) continue;
        const float* hr = h + (size_t)node * EMBD;
        float acc = sB1[lane];
        for (int k = 0; k < EMBD; ++k) acc += hr[k] * sW1[k * EMBD + lane];
        acc = fmaxf(acc, 0.0f);
        float r = acc * sW2[lane];
        for (int o = 32; o > 0; o >>= 1) r += __shfl_down(r, o);
        if (lane == 0) out[node] = r + db2;
    }
}

extern "C" void kernel_launch(void* const* d_in, const int* in_sizes, int n_in,
                              void* d_out, int out_size, void* d_ws, size_t ws_size,
                              hipStream_t stream) {
    const float* x      = (const float*)d_in[0];
    const int*   ei     = (const int*)  d_in[1];
    const float* ew     = (const float*)d_in[2];
    const float* enc_w1 = (const float*)d_in[3];
    const float* enc_b1 = (const float*)d_in[4];
    const float* enc_w2 = (const float*)d_in[5];
    const float* enc_b2 = (const float*)d_in[6];
    const float* gcn_w  = (const float*)d_in[7];
    const float* gcn_b  = (const float*)d_in[8];
    const float* dec_w1 = (const float*)d_in[9];
    const float* dec_b1 = (const float*)d_in[10];
    const float* dec_w2 = (const float*)d_in[11];
    const float* dec_b2 = (const float*)d_in[12];
    float* out = (float*)d_out;

    char* ws = (char*)d_ws;
    size_t off = 0;
    auto alloc = [&](size_t bytes) -> void* {
        void* p = (void*)(ws + off);
        off += (bytes + 511) & ~(size_t)511;
        return p;
    };
    unsigned long long* packed = (unsigned long long*)alloc((size_t)NN * 8);
    float* dis      = (float*)alloc(NN * 4);
    int*   incl     = (int*)  alloc(NN * 4);
    int*   partials = (int*)  alloc(256 * 4);
    int*   row_ptr  = (int*)  alloc((NN + 1) * 4);
    int*   cursor   = (int*)  alloc(NN * 4);
    int2*  edges    = (int2*) alloc((size_t)NE * 8);
    float* hbuf     = (float*)alloc((size_t)NN * EMBD * 4);
    float* hbuf2    = (float*)alloc((size_t)NN * EMBD * 4);
    (void)ws_size; (void)n_in; (void)in_sizes; (void)out_size;

    int gN   = (NN + 255) / 256;
    int gE   = (NE + 255) / 256;
    int gT16 = (NN + 15) / 16;

    k_init<<<gN, 256, 0, stream>>>(packed);
    k_count<<<gE, 256, 0, stream>>>(ei, ew, packed);
    k_dis<<<gN, 256, 0, stream>>>(packed, dis);
    k_scan1<<<SCAN_NBLK, SCAN_B, 0, stream>>>(packed, incl, partials);
    k_scan2<<<1, 1, 0, stream>>>(partials);
    k_scan3<<<gN, 256, 0, stream>>>(packed, incl, partials, row_ptr, cursor);
    k_fill<<<gE, 256, 0, stream>>>(ei, ew, dis, cursor, edges);

    k_encoder<<<gT16, 256, 0, stream>>>(x, enc_w1, enc_b1, enc_w2, enc_b2, hbuf);

    float* cur = hbuf;
    float* nxt = hbuf2;
    for (int layer = 0; layer < NLAY; ++layer) {
        k_layer<<<gT16, 256, 0, stream>>>(cur, dis, row_ptr, edges,
                                          gcn_w + (size_t)layer * EMBD * EMBD,
                                          gcn_b + (size_t)layer * EMBD, nxt);
        float* tmp = cur; cur = nxt; nxt = tmp;
    }

    k_decoder<<<gT16, 256, 0, stream>>>(cur, dec_w1, dec_b1, dec_w2, dec_b2, out);
}

// Round 3
// 605.385 us; speedup vs baseline: 1.3535x; 1.1054x over previous
//
#include <hip/hip_runtime.h>

// FillSimNet: 4-layer GCN forward.
//   1. packed u64 atomics: hi32 = in-degree count, lo32 = fixed-point (2^24) weight sum
//   2. block-scan -> row_ptr, fill CSR (by dst) with packed (col, norm) int2
//   3. encoder MLP (8->64 relu 64->64)
//   4. 4x fused layer: agg = SpMM(norm, h); h = relu(agg @ W + b)
//      gather loop unrolled x4 (4 independent accumulators) for memory-level parallelism
//   5. decoder MLP (64->64 relu 64->1)

constexpr int NN   = 100000;
constexpr int NE   = 1600000;
constexpr int INPD = 8;
constexpr int EMBD = 64;
constexpr int NLAY = 4;
constexpr int SCAN_B = 1024;
constexpr int SCAN_NBLK = (NN + SCAN_B - 1) / SCAN_B; // 98
constexpr float FPSCALE = 16777216.0f;   // 2^24
constexpr int LNODES = 32;               // nodes per k_layer block (512 threads)

__global__ void k_init(unsigned long long* packed) {
    int i = blockIdx.x * blockDim.x + threadIdx.x;
    if (i < NN) packed[i] = (unsigned long long)(1u << 24);  // self-loop weight 1.0, count 0
}

__global__ void k_count(const int* __restrict__ ei, const float* __restrict__ w,
                        unsigned long long* __restrict__ packed) {
    int e = blockIdx.x * blockDim.x + threadIdx.x;
    if (e < NE) {
        int d = ei[NE + e];
        unsigned int fx = (unsigned int)(w[e] * FPSCALE + 0.5f);
        atomicAdd(&packed[d], (1ull << 32) | (unsigned long long)fx);
    }
}

__global__ __launch_bounds__(SCAN_B) void k_scan1(const unsigned long long* __restrict__ packed,
                                                  int* incl, int* partials) {
    __shared__ int s[SCAN_B];
    int tid = threadIdx.x;
    int i = blockIdx.x * SCAN_B + tid;
    int v = (i < NN) ? (int)(packed[i] >> 32) : 0;
    s[tid] = v;
    __syncthreads();
    for (int off = 1; off < SCAN_B; off <<= 1) {
        int t = (tid >= off) ? s[tid - off] : 0;
        __syncthreads();
        s[tid] += t;
        __syncthreads();
    }
    if (i < NN) incl[i] = s[tid];
    if (tid == SCAN_B - 1) partials[blockIdx.x] = s[tid];
}

__global__ void k_scan2(int* partials) {
    if (threadIdx.x == 0 && blockIdx.x == 0) {
        int run = 0;
        for (int b = 0; b < SCAN_NBLK; ++b) {
            int t = partials[b];
            partials[b] = run;
            run += t;
        }
        partials[SCAN_NBLK] = run;  // == NE
    }
}

// also computes dis = 1/sqrt(deg)
__global__ void k_scan3(const unsigned long long* __restrict__ packed,
                        const int* __restrict__ incl, const int* __restrict__ partials,
                        int* row_ptr, int* cursor, float* __restrict__ dis) {
    int i = blockIdx.x * blockDim.x + threadIdx.x;
    if (i < NN) {
        unsigned long long p = packed[i];
        int c = (int)(p >> 32);
        int rp = incl[i] - c + partials[i >> 10];
        row_ptr[i] = rp;
        cursor[i] = rp;
        float deg = (float)(unsigned int)(p & 0xffffffffull) * (1.0f / FPSCALE);
        dis[i] = 1.0f / sqrtf(deg);   // deg >= 1 always
        if (i == 0) row_ptr[NN] = partials[SCAN_NBLK];
    }
}

__global__ void k_fill(const int* __restrict__ ei, const float* __restrict__ w,
                       const float* __restrict__ dis,
                       int* __restrict__ cursor, int2* __restrict__ edges) {
    int e = blockIdx.x * blockDim.x + threadIdx.x;
    if (e < NE) {
        int s = ei[e];
        int d = ei[NE + e];
        int pos = atomicAdd(&cursor[d], 1);
        float nv = dis[s] * w[e] * dis[d];
        edges[pos] = make_int2(s, __float_as_int(nv));
    }
}

// encoder: h = relu(x@W1+b1)@W2 + b2 ; 16 nodes per 256-thread block
__global__ __launch_bounds__(256) void k_encoder(const float* __restrict__ x,
                                                 const float* __restrict__ w1,
                                                 const float* __restrict__ b1,
                                                 const float* __restrict__ w2,
                                                 const float* __restrict__ b2,
                                                 float* __restrict__ h) {
    __shared__ float sW1[INPD * EMBD];
    __shared__ float sW2[EMBD * EMBD];
    __shared__ float sB1[EMBD];
    __shared__ float sB2[EMBD];
    __shared__ float sZ[16][EMBD];
    int tid = threadIdx.x;
    for (int i = tid; i < INPD * EMBD; i += 256) sW1[i] = w1[i];
    for (int i = tid; i < EMBD * EMBD; i += 256) sW2[i] = w2[i];
    if (tid < EMBD) { sB1[tid] = b1[tid]; sB2[tid] = b2[tid]; }
    __syncthreads();
    int base = blockIdx.x * 16;
    #pragma unroll
    for (int it = 0; it < 4; ++it) {
        int item = tid + it * 256;
        int nl = item >> 6, j = item & 63;
        int node = base + nl;
        float acc = sB1[j];
        if (node < NN) {
            const float* xr = x + (size_t)node * INPD;
            #pragma unroll
            for (int k = 0; k < INPD; ++k) acc += xr[k] * sW1[k * EMBD + j];
        }
        sZ[nl][j] = fmaxf(acc, 0.0f);
    }
    __syncthreads();
    #pragma unroll
    for (int it = 0; it < 4; ++it) {
        int item = tid + it * 256;
        int nl = item >> 6, j2 = item & 63;
        int node = base + nl;
        if (node < NN) {
            float acc = sB2[j2];
            for (int j = 0; j < EMBD; ++j) acc += sZ[nl][j] * sW2[j * EMBD + j2];
            h[(size_t)node * EMBD + j2] = acc;
        }
    }
}

// fused layer: agg = dis[n]^2*h[n] + sum_e norm[e]*h[col[e]] ; hout = relu(agg @ W + b)
// 32 nodes / 512-thread block; 16 lanes per node; edge loop unrolled x4
__global__ __launch_bounds__(512) void k_layer(const float* __restrict__ hin,
                                               const float* __restrict__ dis,
                                               const int* __restrict__ row_ptr,
                                               const int2* __restrict__ edges,
                                               const float* __restrict__ W,
                                               const float* __restrict__ bias,
                                               float* __restrict__ hout) {
    __shared__ float sW[EMBD * EMBD];
    __shared__ float sB[EMBD];
    __shared__ float sA[LNODES][EMBD];
    int tid = threadIdx.x;
    for (int i = tid; i < EMBD * EMBD; i += 512) sW[i] = W[i];
    if (tid < EMBD) sB[tid] = bias[tid];

    int g = tid >> 4, l = tid & 15;
    int node = blockIdx.x * LNODES + g;
    const float4* h4 = (const float4*)hin;
    float4 a0 = make_float4(0.f, 0.f, 0.f, 0.f);
    float4 a1 = a0, a2 = a0, a3 = a0;
    if (node < NN) {
        float dsn = dis[node];
        float sn = dsn * dsn;
        a0 = h4[(size_t)node * 16 + l];
        a0.x *= sn; a0.y *= sn; a0.z *= sn; a0.w *= sn;
        int beg = row_ptr[node], end = row_ptr[node + 1];
        int e = beg;
        for (; e + 4 <= end; e += 4) {
            int2 e0 = edges[e], e1 = edges[e + 1], e2 = edges[e + 2], e3 = edges[e + 3];
            float4 t0 = h4[(size_t)e0.x * 16 + l];
            float4 t1 = h4[(size_t)e1.x * 16 + l];
            float4 t2 = h4[(size_t)e2.x * 16 + l];
            float4 t3 = h4[(size_t)e3.x * 16 + l];
            float v0 = __int_as_float(e0.y), v1 = __int_as_float(e1.y);
            float v2 = __int_as_float(e2.y), v3 = __int_as_float(e3.y);
            a0.x += v0 * t0.x; a0.y += v0 * t0.y; a0.z += v0 * t0.z; a0.w += v0 * t0.w;
            a1.x += v1 * t1.x; a1.y += v1 * t1.y; a1.z += v1 * t1.z; a1.w += v1 * t1.w;
            a2.x += v2 * t2.x; a2.y += v2 * t2.y; a2.z += v2 * t2.z; a2.w += v2 * t2.w;
            a3.x += v3 * t3.x; a3.y += v3 * t3.y; a3.z += v3 * t3.z; a3.w += v3 * t3.w;
        }
        for (; e < end; ++e) {
            int2 ev = edges[e];
            float v = __int_as_float(ev.y);
            float4 tv = h4[(size_t)ev.x * 16 + l];
            a0.x += v * tv.x; a0.y += v * tv.y; a0.z += v * tv.z; a0.w += v * tv.w;
        }
    }
    a0.x += a1.x + a2.x + a3.x;
    a0.y += a1.y + a2.y + a3.y;
    a0.z += a1.z + a2.z + a3.z;
    a0.w += a1.w + a2.w + a3.w;
    ((float4*)&sA[g][0])[l] = a0;
    __syncthreads();

    int base = blockIdx.x * LNODES;
    #pragma unroll
    for (int it = 0; it < 4; ++it) {
        int item = tid + it * 512;
        int nl = item >> 6, j2 = item & 63;
        int onode = base + nl;
        if (onode < NN) {
            float o = sB[j2];
            for (int k = 0; k < EMBD; ++k) o += sA[nl][k] * sW[k * EMBD + j2];
            hout[(size_t)onode * EMBD + j2] = fmaxf(o, 0.0f);
        }
    }
}

// out = relu(h@W1+b1)@W2 + b2 (OUT=1) ; one wave per node, 4 nodes/wave serial
__global__ __launch_bounds__(256) void k_decoder(const float* __restrict__ h,
                                                 const float* __restrict__ w1,
                                                 const float* __restrict__ b1,
                                                 const float* __restrict__ w2,
                                                 const float* __restrict__ b2,
                                                 float* __restrict__ out) {
    __shared__ float sW1[EMBD * EMBD];
    __shared__ float sB1[EMBD];
    __shared__ float sW2[EMBD];
    int tid = threadIdx.x;
    for (int i = tid; i < EMBD * EMBD; i += 256) sW1[i] = w1[i];
    if (tid < EMBD) { sB1[tid] = b1[tid]; sW2[tid] = w2[tid]; }
    __syncthreads();
    int wave = tid >> 6, lane = tid & 63;
    float db2 = b2[0];
    #pragma unroll
    for (int it = 0; it < 4; ++it) {
        int node = blockIdx.x * 16 + wave * 4 + it;
        if (node >= NN) continue;
        const float* hr = h + (size_t)node * EMBD;
        float acc = sB1[lane];
        for (int k = 0; k < EMBD; ++k) acc += hr[k] * sW1[k * EMBD + lane];
        acc = fmaxf(acc, 0.0f);
        float r = acc * sW2[lane];
        for (int o = 32; o > 0; o >>= 1) r += __shfl_down(r, o);
        if (lane == 0) out[node] = r + db2;
    }
}

extern "C" void kernel_launch(void* const* d_in, const int* in_sizes, int n_in,
                              void* d_out, int out_size, void* d_ws, size_t ws_size,
                              hipStream_t stream) {
    const float* x      = (const float*)d_in[0];
    const int*   ei     = (const int*)  d_in[1];
    const float* ew     = (const float*)d_in[2];
    const float* enc_w1 = (const float*)d_in[3];
    const float* enc_b1 = (const float*)d_in[4];
    const float* enc_w2 = (const float*)d_in[5];
    const float* enc_b2 = (const float*)d_in[6];
    const float* gcn_w  = (const float*)d_in[7];
    const float* gcn_b  = (const float*)d_in[8];
    const float* dec_w1 = (const float*)d_in[9];
    const float* dec_b1 = (const float*)d_in[10];
    const float* dec_w2 = (const float*)d_in[11];
    const float* dec_b2 = (const float*)d_in[12];
    float* out = (float*)d_out;

    char* ws = (char*)d_ws;
    size_t off = 0;
    auto alloc = [&](size_t bytes) -> void* {
        void* p = (void*)(ws + off);
        off += (bytes + 511) & ~(size_t)511;
        return p;
    };
    unsigned long long* packed = (unsigned long long*)alloc((size_t)NN * 8);
    float* dis      = (float*)alloc(NN * 4);
    int*   incl     = (int*)  alloc(NN * 4);
    int*   partials = (int*)  alloc(256 * 4);
    int*   row_ptr  = (int*)  alloc((NN + 1) * 4);
    int*   cursor   = (int*)  alloc(NN * 4);
    int2*  edges    = (int2*) alloc((size_t)NE * 8);
    float* hbuf     = (float*)alloc((size_t)NN * EMBD * 4);
    float* hbuf2    = (float*)alloc((size_t)NN * EMBD * 4);
    (void)ws_size; (void)n_in; (void)in_sizes; (void)out_size;

    int gN   = (NN + 255) / 256;
    int gE   = (NE + 255) / 256;
    int gT16 = (NN + 15) / 16;
    int gL   = (NN + LNODES - 1) / LNODES;

    k_init<<<gN, 256, 0, stream>>>(packed);
    k_count<<<gE, 256, 0, stream>>>(ei, ew, packed);
    k_scan1<<<SCAN_NBLK, SCAN_B, 0, stream>>>(packed, incl, partials);
    k_scan2<<<1, 1, 0, stream>>>(partials);
    k_scan3<<<gN, 256, 0, stream>>>(packed, incl, partials, row_ptr, cursor, dis);
    k_fill<<<gE, 256, 0, stream>>>(ei, ew, dis, cursor, edges);

    k_encoder<<<gT16, 256, 0, stream>>>(x, enc_w1, enc_b1, enc_w2, enc_b2, hbuf);

    float* cur = hbuf;
    float* nxt = hbuf2;
    for (int layer = 0; layer < NLAY; ++layer) {
        k_layer<<<gL, 512, 0, stream>>>(cur, dis, row_ptr, edges,
                                        gcn_w + (size_t)layer * EMBD * EMBD,
                                        gcn_b + (size_t)layer * EMBD, nxt);
        float* tmp = cur; cur = nxt; nxt = tmp;
    }

    k_decoder<<<gT16, 256, 0, stream>>>(cur, dec_w1, dec_b1, dec_w2, dec_b2, out);
}